// Round 2
// baseline (280.246 us; speedup 1.0000x reference)
//
#include <hip/hip_runtime.h>

// MSE over remapped (norms, labels):
//   label==1: n *= 10, target = 10
//   label==2: n *= 5,  target = 20
//   else:     n *= 1,  target = 0  (label==0 -> 0 either way)
// out[0] = mean((n - target)^2) over 4096*8192 elements.

__device__ __forceinline__ float remap_sq(float n, float lab) {
    // branchless remap via predication (G5)
    float sn  = (lab == 1.0f) ? 10.0f : ((lab == 2.0f) ? 5.0f : 1.0f);
    float tgt = lab * 10.0f;                 // 0 / 10 / 20
    float d   = fmaf(n, sn, -tgt);
    return d * d;
}

__global__ __launch_bounds__(256) void mse_remap_kernel(
    const float* __restrict__ norms,
    const float* __restrict__ labels,
    float* __restrict__ out,
    size_t n4, size_t n, float inv_n)
{
    const float4* np4 = reinterpret_cast<const float4*>(norms);
    const float4* lp4 = reinterpret_cast<const float4*>(labels);

    size_t tid    = (size_t)blockIdx.x * blockDim.x + threadIdx.x;
    size_t stride = (size_t)gridDim.x * blockDim.x;

    float acc = 0.0f;
    for (size_t i = tid; i < n4; i += stride) {
        float4 nv = np4[i];
        float4 lv = lp4[i];
        acc += remap_sq(nv.x, lv.x);
        acc += remap_sq(nv.y, lv.y);
        acc += remap_sq(nv.z, lv.z);
        acc += remap_sq(nv.w, lv.w);
    }
    // scalar tail (n % 4 != 0 — not hit for 4096*8192, defensive only)
    for (size_t i = n4 * 4 + tid; i < n; i += stride)
        acc += remap_sq(norms[i], labels[i]);

    // wave-64 butterfly reduction
#pragma unroll
    for (int off = 32; off > 0; off >>= 1)
        acc += __shfl_down(acc, off, 64);

    __shared__ float wsum[4];                // 256 threads = 4 waves
    int lane = threadIdx.x & 63;
    int wid  = threadIdx.x >> 6;
    if (lane == 0) wsum[wid] = acc;
    __syncthreads();

    if (threadIdx.x == 0) {
        float s = (wsum[0] + wsum[1]) + (wsum[2] + wsum[3]);
        atomicAdd(out, s * inv_n);           // one device-scope atomic per block (G12)
    }
}

extern "C" void kernel_launch(void* const* d_in, const int* in_sizes, int n_in,
                              void* d_out, int out_size, void* d_ws, size_t ws_size,
                              hipStream_t stream)
{
    const float* norms  = (const float*)d_in[0];
    const float* labels = (const float*)d_in[1];
    float* out = (float*)d_out;

    size_t n  = (size_t)in_sizes[0];         // 4096*8192 = 33,554,432
    size_t n4 = n / 4;
    float inv_n = 1.0f / (float)n;

    // d_out is poisoned to 0xAA before every launch — zero the accumulator.
    hipMemsetAsync(out, 0, sizeof(float), stream);

    // 2048 blocks * 256 threads, grid-stride (G11).
    mse_remap_kernel<<<2048, 256, 0, stream>>>(norms, labels, out, n4, n, inv_n);
}

// Round 3
// 272.460 us; speedup vs baseline: 1.0286x; 1.0286x over previous
//
#include <hip/hip_runtime.h>

// MSE over remapped (norms, labels):
//   label==1: n *= 10, target = 10
//   label==2: n *= 5,  target = 20
//   else:     n *= 1,  target = 0
// out[0] = mean((n - target)^2) over 4096*8192 f32 elements.
//
// Memory-bound streaming reduction. Round-2 lesson: compiler does NOT unroll
// the grid-stride loop (VGPR=12, vmcnt(0) every iteration -> latency-bound at
// 2.5 TB/s). Manual x4 unroll batches 8 float4 loads per iteration for MLP.

__device__ __forceinline__ float remap_sq(float n, float lab) {
    float sn  = (lab == 1.0f) ? 10.0f : ((lab == 2.0f) ? 5.0f : 1.0f);
    float tgt = lab * 10.0f;                 // 0 / 10 / 20
    float d   = fmaf(n, sn, -tgt);
    return d * d;
}

__device__ __forceinline__ float remap_sq4(float4 n, float4 l) {
    return remap_sq(n.x, l.x) + remap_sq(n.y, l.y)
         + remap_sq(n.z, l.z) + remap_sq(n.w, l.w);
}

__global__ __launch_bounds__(256) void mse_remap_kernel(
    const float* __restrict__ norms,
    const float* __restrict__ labels,
    float* __restrict__ out,
    size_t n4, size_t n, float inv_n)
{
    const float4* np4 = reinterpret_cast<const float4*>(norms);
    const float4* lp4 = reinterpret_cast<const float4*>(labels);

    size_t tid    = (size_t)blockIdx.x * blockDim.x + threadIdx.x;
    size_t stride = (size_t)gridDim.x * blockDim.x;

    float acc = 0.0f;
    size_t i = tid;

    // Main loop: 4 stride-points per iteration, all 8 loads issued before
    // any consumption -> 128 B/lane in flight (vs 32 B unrolled-by-1).
    for (; i + 3 * stride < n4; i += 4 * stride) {
        float4 a0 = np4[i];
        float4 a1 = np4[i +     stride];
        float4 a2 = np4[i + 2 * stride];
        float4 a3 = np4[i + 3 * stride];
        float4 b0 = lp4[i];
        float4 b1 = lp4[i +     stride];
        float4 b2 = lp4[i + 2 * stride];
        float4 b3 = lp4[i + 3 * stride];
        acc += remap_sq4(a0, b0);
        acc += remap_sq4(a1, b1);
        acc += remap_sq4(a2, b2);
        acc += remap_sq4(a3, b3);
    }
    // float4 remainder (not hit at 4096x8192 with grid 2048x256)
    for (; i < n4; i += stride) {
        float4 a = np4[i];
        float4 b = lp4[i];
        acc += remap_sq4(a, b);
    }
    // scalar remainder (n % 4 != 0 — defensive only)
    for (size_t j = n4 * 4 + tid; j < n; j += stride)
        acc += remap_sq(norms[j], labels[j]);

    // wave-64 butterfly reduction
#pragma unroll
    for (int off = 32; off > 0; off >>= 1)
        acc += __shfl_down(acc, off, 64);

    __shared__ float wsum[4];                // 256 threads = 4 waves
    int lane = threadIdx.x & 63;
    int wid  = threadIdx.x >> 6;
    if (lane == 0) wsum[wid] = acc;
    __syncthreads();

    if (threadIdx.x == 0) {
        float s = (wsum[0] + wsum[1]) + (wsum[2] + wsum[3]);
        atomicAdd(out, s * inv_n);           // one device-scope atomic per block
    }
}

extern "C" void kernel_launch(void* const* d_in, const int* in_sizes, int n_in,
                              void* d_out, int out_size, void* d_ws, size_t ws_size,
                              hipStream_t stream)
{
    const float* norms  = (const float*)d_in[0];
    const float* labels = (const float*)d_in[1];
    float* out = (float*)d_out;

    size_t n  = (size_t)in_sizes[0];         // 4096*8192 = 33,554,432
    size_t n4 = n / 4;
    float inv_n = 1.0f / (float)n;

    // d_out is poisoned to 0xAA before every launch — zero the accumulator.
    hipMemsetAsync(out, 0, sizeof(float), stream);

    // 2048 blocks * 256 threads = max-resident grid; 16 float4/thread,
    // i.e. exactly 4 unrolled main-loop iterations.
    mse_remap_kernel<<<2048, 256, 0, stream>>>(norms, labels, out, n4, n, inv_n);
}

// Round 5
// 256.940 us; speedup vs baseline: 1.0907x; 1.0604x over previous
//
#include <hip/hip_runtime.h>

// MSE over remapped (norms, labels):
//   label==1: n *= 10, target = 10
//   label==2: n *= 5,  target = 20
//   else:     n *= 1,  target = 0
// out[0] = mean((n - target)^2) over 4096*8192 f32 elements.
//
// Round-3 lesson: in-wave MLP (x4 unroll) did NOT move the 2.65 TB/s read
// wall -> suspect per-CU L1 miss-tracking limit. This round: nontemporal
// (streaming, no-allocate) loads to bypass L1/L2 allocation for this
// single-use data.

typedef float f4 __attribute__((ext_vector_type(4)));

__device__ __forceinline__ float remap_sq(float n, float lab) {
    float sn  = (lab == 1.0f) ? 10.0f : ((lab == 2.0f) ? 5.0f : 1.0f);
    float tgt = lab * 10.0f;                 // 0 / 10 / 20
    float d   = fmaf(n, sn, -tgt);
    return d * d;
}

__device__ __forceinline__ float remap_sq4(f4 n, f4 l) {
    return remap_sq(n.x, l.x) + remap_sq(n.y, l.y)
         + remap_sq(n.z, l.z) + remap_sq(n.w, l.w);
}

__global__ __launch_bounds__(256) void mse_remap_kernel(
    const float* __restrict__ norms,
    const float* __restrict__ labels,
    float* __restrict__ out,
    size_t n4, size_t n, float inv_n)
{
    const f4* np4 = reinterpret_cast<const f4*>(norms);
    const f4* lp4 = reinterpret_cast<const f4*>(labels);

    size_t tid    = (size_t)blockIdx.x * blockDim.x + threadIdx.x;
    size_t stride = (size_t)gridDim.x * blockDim.x;

    float acc = 0.0f;
    size_t i = tid;

    // Main loop: 4 stride-points/iter, 8 nontemporal float4 loads batched.
    for (; i + 3 * stride < n4; i += 4 * stride) {
        f4 a0 = __builtin_nontemporal_load(&np4[i]);
        f4 a1 = __builtin_nontemporal_load(&np4[i +     stride]);
        f4 a2 = __builtin_nontemporal_load(&np4[i + 2 * stride]);
        f4 a3 = __builtin_nontemporal_load(&np4[i + 3 * stride]);
        f4 b0 = __builtin_nontemporal_load(&lp4[i]);
        f4 b1 = __builtin_nontemporal_load(&lp4[i +     stride]);
        f4 b2 = __builtin_nontemporal_load(&lp4[i + 2 * stride]);
        f4 b3 = __builtin_nontemporal_load(&lp4[i + 3 * stride]);
        acc += remap_sq4(a0, b0);
        acc += remap_sq4(a1, b1);
        acc += remap_sq4(a2, b2);
        acc += remap_sq4(a3, b3);
    }
    // float4 remainder (not hit at 4096x8192 with grid 2048x256)
    for (; i < n4; i += stride) {
        f4 a = __builtin_nontemporal_load(&np4[i]);
        f4 b = __builtin_nontemporal_load(&lp4[i]);
        acc += remap_sq4(a, b);
    }
    // scalar remainder (defensive only)
    for (size_t j = n4 * 4 + tid; j < n; j += stride)
        acc += remap_sq(norms[j], labels[j]);

    // wave-64 butterfly reduction
#pragma unroll
    for (int off = 32; off > 0; off >>= 1)
        acc += __shfl_down(acc, off, 64);

    __shared__ float wsum[4];                // 256 threads = 4 waves
    int lane = threadIdx.x & 63;
    int wid  = threadIdx.x >> 6;
    if (lane == 0) wsum[wid] = acc;
    __syncthreads();

    if (threadIdx.x == 0) {
        float s = (wsum[0] + wsum[1]) + (wsum[2] + wsum[3]);
        atomicAdd(out, s * inv_n);           // one device-scope atomic per block
    }
}

extern "C" void kernel_launch(void* const* d_in, const int* in_sizes, int n_in,
                              void* d_out, int out_size, void* d_ws, size_t ws_size,
                              hipStream_t stream)
{
    const float* norms  = (const float*)d_in[0];
    const float* labels = (const float*)d_in[1];
    float* out = (float*)d_out;

    size_t n  = (size_t)in_sizes[0];         // 4096*8192 = 33,554,432
    size_t n4 = n / 4;
    float inv_n = 1.0f / (float)n;

    // d_out is poisoned to 0xAA before every launch — zero the accumulator.
    hipMemsetAsync(out, 0, sizeof(float), stream);

    // 2048 blocks * 256 threads, grid-stride; 16 float4/thread.
    mse_remap_kernel<<<2048, 256, 0, stream>>>(norms, labels, out, n4, n, inv_n);
}

// Round 6
// 256.152 us; speedup vs baseline: 1.0941x; 1.0031x over previous
//
#include <hip/hip_runtime.h>

// MSE over remapped (norms, labels):
//   label==1: n *= 10, target = 10
//   label==2: n *= 5,  target = 20
//   else:     n *= 1,  target = 0
// out[0] = mean((n - target)^2) over 4096*8192 f32 elements.
//
// Ladder: naive grid-stride 105us -> x4 unroll 101us -> +nontemporal <78us
// (nt bypasses L1-allocate tracking; confirmed round 5). This round: x8
// unroll -> 16 nt float4 loads batched (256 B/lane in flight) to double
// per-wave MLP now that the L1 wall is gone.

typedef float f4 __attribute__((ext_vector_type(4)));

__device__ __forceinline__ float remap_sq(float n, float lab) {
    float sn  = (lab == 1.0f) ? 10.0f : ((lab == 2.0f) ? 5.0f : 1.0f);
    float tgt = lab * 10.0f;                 // 0 / 10 / 20
    float d   = fmaf(n, sn, -tgt);
    return d * d;
}

__device__ __forceinline__ float remap_sq4(f4 n, f4 l) {
    return remap_sq(n.x, l.x) + remap_sq(n.y, l.y)
         + remap_sq(n.z, l.z) + remap_sq(n.w, l.w);
}

__global__ __launch_bounds__(256) void mse_remap_kernel(
    const float* __restrict__ norms,
    const float* __restrict__ labels,
    float* __restrict__ out,
    size_t n4, size_t n, float inv_n)
{
    const f4* np4 = reinterpret_cast<const f4*>(norms);
    const f4* lp4 = reinterpret_cast<const f4*>(labels);

    size_t tid    = (size_t)blockIdx.x * blockDim.x + threadIdx.x;
    size_t stride = (size_t)gridDim.x * blockDim.x;

    float acc = 0.0f;
    size_t i = tid;

    // Main loop: 8 stride-points/iter, 16 nt float4 loads batched before any
    // consumption. At 4096x8192 with grid 2048x256: exactly 2 iterations.
    for (; i + 7 * stride < n4; i += 8 * stride) {
        f4 a0 = __builtin_nontemporal_load(&np4[i]);
        f4 a1 = __builtin_nontemporal_load(&np4[i +     stride]);
        f4 a2 = __builtin_nontemporal_load(&np4[i + 2 * stride]);
        f4 a3 = __builtin_nontemporal_load(&np4[i + 3 * stride]);
        f4 a4 = __builtin_nontemporal_load(&np4[i + 4 * stride]);
        f4 a5 = __builtin_nontemporal_load(&np4[i + 5 * stride]);
        f4 a6 = __builtin_nontemporal_load(&np4[i + 6 * stride]);
        f4 a7 = __builtin_nontemporal_load(&np4[i + 7 * stride]);
        f4 b0 = __builtin_nontemporal_load(&lp4[i]);
        f4 b1 = __builtin_nontemporal_load(&lp4[i +     stride]);
        f4 b2 = __builtin_nontemporal_load(&lp4[i + 2 * stride]);
        f4 b3 = __builtin_nontemporal_load(&lp4[i + 3 * stride]);
        f4 b4 = __builtin_nontemporal_load(&lp4[i + 4 * stride]);
        f4 b5 = __builtin_nontemporal_load(&lp4[i + 5 * stride]);
        f4 b6 = __builtin_nontemporal_load(&lp4[i + 6 * stride]);
        f4 b7 = __builtin_nontemporal_load(&lp4[i + 7 * stride]);
        acc += remap_sq4(a0, b0);
        acc += remap_sq4(a1, b1);
        acc += remap_sq4(a2, b2);
        acc += remap_sq4(a3, b3);
        acc += remap_sq4(a4, b4);
        acc += remap_sq4(a5, b5);
        acc += remap_sq4(a6, b6);
        acc += remap_sq4(a7, b7);
    }
    // float4 remainder (not hit at this size — defensive)
    for (; i < n4; i += stride) {
        f4 a = __builtin_nontemporal_load(&np4[i]);
        f4 b = __builtin_nontemporal_load(&lp4[i]);
        acc += remap_sq4(a, b);
    }
    // scalar remainder (defensive only)
    for (size_t j = n4 * 4 + tid; j < n; j += stride)
        acc += remap_sq(norms[j], labels[j]);

    // wave-64 butterfly reduction
#pragma unroll
    for (int off = 32; off > 0; off >>= 1)
        acc += __shfl_down(acc, off, 64);

    __shared__ float wsum[4];                // 256 threads = 4 waves
    int lane = threadIdx.x & 63;
    int wid  = threadIdx.x >> 6;
    if (lane == 0) wsum[wid] = acc;
    __syncthreads();

    if (threadIdx.x == 0) {
        float s = (wsum[0] + wsum[1]) + (wsum[2] + wsum[3]);
        atomicAdd(out, s * inv_n);           // one device-scope atomic per block
    }
}

extern "C" void kernel_launch(void* const* d_in, const int* in_sizes, int n_in,
                              void* d_out, int out_size, void* d_ws, size_t ws_size,
                              hipStream_t stream)
{
    const float* norms  = (const float*)d_in[0];
    const float* labels = (const float*)d_in[1];
    float* out = (float*)d_out;

    size_t n  = (size_t)in_sizes[0];         // 4096*8192 = 33,554,432
    size_t n4 = n / 4;
    float inv_n = 1.0f / (float)n;

    // d_out is poisoned to 0xAA before every launch — zero the accumulator.
    hipMemsetAsync(out, 0, sizeof(float), stream);

    // 2048 blocks * 256 threads, grid-stride; 16 float4/thread = 2 main iters.
    mse_remap_kernel<<<2048, 256, 0, stream>>>(norms, labels, out, n4, n, inv_n);
}